// Round 1
// baseline (61.044 us; speedup 1.0000x reference)
//
#include <hip/hip_runtime.h>

// Tensor-train gather: out[q] = sum_{a,b} g0[0,i0,a] * g1[a,i1,b] * g2[b,i2,0]
// g0: (1,320,16)  row-major [i0*16 + a]
// g1: (16,320,16) [a*5120 + i1*16 + b]
// g2: (16,320,1)  [b*320 + i2]
//
// One query per wave64 (vs 16-lanes/query before): 8192 waves total
// -> 8 waves/SIMD occupancy (was 2), SGPR-uniform indices, one
// global_load_dwordx4 per lane for the whole 16x16 G1 slice per wave.
// Lane l: row a = l>>2 (0..15), column quad c = l&3 (covers b = 4c..4c+3).

__global__ __launch_bounds__(256, 8) void tt_gather_kernel(
    const float* __restrict__ g0,
    const float* __restrict__ g1,
    const float* __restrict__ g2,
    const int* __restrict__ idxs,
    float* __restrict__ out,
    int N)
{
    const int wave = threadIdx.x >> 6;            // 0..3 within block
    const int lane = threadIdx.x & 63;
    const int q = blockIdx.x * 4 + wave;          // one query per wave
    if (q >= N) return;                           // wave-uniform exit

    // Wave-uniform indices -> force into SGPRs so every load below is
    // SGPR-base + lane-constant VGPR offset.
    int i0 = idxs[3 * q + 0];
    int i1 = idxs[3 * q + 1];
    int i2 = idxs[3 * q + 2];
    i0 = __builtin_amdgcn_readfirstlane(i0);
    i1 = __builtin_amdgcn_readfirstlane(i1);
    i2 = __builtin_amdgcn_readfirstlane(i2);

    const int a = lane >> 2;                      // G1 slice row 0..15
    const int c = lane & 3;                       // column quad 0..3

    // Whole 16x16 slice fetched by one dwordx4 per lane (16B aligned:
    // (a*5120 + i1*16 + c*4)*4 bytes is a multiple of 16).
    const float4 gv = *reinterpret_cast<const float4*>(
        g1 + a * 5120 + i1 * 16 + c * 4);

    // g2 column entries b = 4c..4c+3. Per instruction the wave touches only
    // 4 distinct addresses (broadcast within 16-lane cohorts); g2 is 20 KB,
    // L1-resident.
    const float s0 = g2[(4 * c + 0) * 320 + i2];
    const float s1 = g2[(4 * c + 1) * 320 + i2];
    const float s2 = g2[(4 * c + 2) * 320 + i2];
    const float s3 = g2[(4 * c + 3) * 320 + i2];

    // g0 row entry for this lane's a (16 distinct addrs per wave, one 64B line).
    const float g0a = g0[i0 * 16 + a];

    float p = g0a * (gv.x * s0 + gv.y * s1 + gv.z * s2 + gv.w * s3);

    // Full 64-lane reduction.
#pragma unroll
    for (int off = 32; off >= 1; off >>= 1)
        p += __shfl_xor(p, off, 64);

    if (lane == 0) out[q] = p;
}

extern "C" void kernel_launch(void* const* d_in, const int* in_sizes, int n_in,
                              void* d_out, int out_size, void* d_ws, size_t ws_size,
                              hipStream_t stream) {
    const float* g0 = (const float*)d_in[0];
    const float* g1 = (const float*)d_in[1];
    const float* g2 = (const float*)d_in[2];
    const int* idxs = (const int*)d_in[3];
    float* out = (float*)d_out;

    const int N = in_sizes[3] / 3;          // 8192 queries
    const int block = 256;                  // 4 waves = 4 queries per block
    const int grid = (N + 3) / 4;           // one query per wave

    tt_gather_kernel<<<grid, block, 0, stream>>>(g0, g1, g2, idxs, out, N);
}

// Round 2
// 60.818 us; speedup vs baseline: 1.0037x; 1.0037x over previous
//
#include <hip/hip_runtime.h>

// Tensor-train gather: out[q] = sum_{a,b} g0[0,i0,a] * g1[a,i1,b] * g2[b,i2,0]
// g0: (1,320,16)  [i0*16 + a]
// g1: (16,320,16) [a*5120 + i1*16 + b]
// g2: (16,320,1)  [b*320 + i2]
//
// 4 queries per wave64 (ILP over the latency chain):
//  - 12 idx ints per quad are contiguous + 16B-aligned -> 3 broadcast dwordx4
//  - 4 independent g1 dwordx4 + 4 g0 + 16 g2 loads all issue before one wait
//  - 4 interleaved 6-step shfl reduces (independent, they pipeline)
//  - one dwordx4 store per wave
// Lane l: row a = l>>2 (0..15), column quad c = l&3 (b = 4c..4c+3).

__global__ __launch_bounds__(256) void tt_gather_kernel(
    const float* __restrict__ g0,
    const float* __restrict__ g1,
    const float* __restrict__ g2,
    const int* __restrict__ idxs,
    float* __restrict__ out,
    int N)
{
    const int wave = threadIdx.x >> 6;
    const int lane = threadIdx.x & 63;
    const int qbase = (blockIdx.x * 4 + wave) * 4;   // 4 queries per wave
    if (qbase >= N) return;                           // wave-uniform exit

    const int a = lane >> 2;                          // G1 slice row 0..15
    const int c = lane & 3;                           // column quad 0..3

    int i0[4], i1[4], i2[4];

    if (qbase + 3 < N) {
        // Fast path: 12 consecutive ints = 3 broadcast dwordx4 loads.
        const int4* ip = reinterpret_cast<const int4*>(idxs + 3 * qbase);
        const int4 A = ip[0], B = ip[1], C = ip[2];
        i0[0] = A.x; i1[0] = A.y; i2[0] = A.z;
        i0[1] = A.w; i1[1] = B.x; i2[1] = B.y;
        i0[2] = B.z; i1[2] = B.w; i2[2] = C.x;
        i0[3] = C.y; i1[3] = C.z; i2[3] = C.w;
    } else {
        // Tail (not hit at N=8192, kept for safety).
#pragma unroll
        for (int j = 0; j < 4; ++j) {
            const int q = qbase + j < N ? qbase + j : N - 1;
            i0[j] = idxs[3 * q + 0];
            i1[j] = idxs[3 * q + 1];
            i2[j] = idxs[3 * q + 2];
        }
    }

    // Wave-uniform -> SGPRs; all data loads become SGPR-base + const offsets.
#pragma unroll
    for (int j = 0; j < 4; ++j) {
        i0[j] = __builtin_amdgcn_readfirstlane(i0[j]);
        i1[j] = __builtin_amdgcn_readfirstlane(i1[j]);
        i2[j] = __builtin_amdgcn_readfirstlane(i2[j]);
    }

    // 4 independent 16B g1 loads (16 cache lines per instr, L2-resident).
    float4 gv[4];
#pragma unroll
    for (int j = 0; j < 4; ++j)
        gv[j] = *reinterpret_cast<const float4*>(g1 + a * 5120 + i1[j] * 16 + c * 4);

    // g0 row entries (16 distinct addrs per instr, one cache line).
    float g0a[4];
#pragma unroll
    for (int j = 0; j < 4; ++j)
        g0a[j] = g0[i0[j] * 16 + a];

    // g2 entries: 4 distinct addrs per instr (broadcast in 16-lane cohorts).
    float p[4];
#pragma unroll
    for (int j = 0; j < 4; ++j) {
        const float s0 = g2[(4 * c + 0) * 320 + i2[j]];
        const float s1 = g2[(4 * c + 1) * 320 + i2[j]];
        const float s2 = g2[(4 * c + 2) * 320 + i2[j]];
        const float s3 = g2[(4 * c + 3) * 320 + i2[j]];
        p[j] = g0a[j] * (gv[j].x * s0 + gv[j].y * s1 +
                         gv[j].z * s2 + gv[j].w * s3);
    }

    // 4 interleaved full-wave reductions (independent -> pipelined).
#pragma unroll
    for (int off = 32; off >= 1; off >>= 1) {
#pragma unroll
        for (int j = 0; j < 4; ++j)
            p[j] += __shfl_xor(p[j], off, 64);
    }

    if (lane == 0) {
        if (qbase + 3 < N) {
            *reinterpret_cast<float4*>(out + qbase) =
                make_float4(p[0], p[1], p[2], p[3]);
        } else {
#pragma unroll
            for (int j = 0; j < 4; ++j)
                if (qbase + j < N) out[qbase + j] = p[j];
        }
    }
}

extern "C" void kernel_launch(void* const* d_in, const int* in_sizes, int n_in,
                              void* d_out, int out_size, void* d_ws, size_t ws_size,
                              hipStream_t stream) {
    const float* g0 = (const float*)d_in[0];
    const float* g1 = (const float*)d_in[1];
    const float* g2 = (const float*)d_in[2];
    const int* idxs = (const int*)d_in[3];
    float* out = (float*)d_out;

    const int N = in_sizes[3] / 3;            // 8192 queries
    const int block = 256;                    // 4 waves -> 16 queries per block
    const int grid = (N + 15) / 16;

    tt_gather_kernel<<<grid, block, 0, stream>>>(g0, g1, g2, idxs, out, N);
}